// Round 2
// baseline (1525.242 us; speedup 1.0000x reference)
//
#include <hip/hip_runtime.h>
#include <hip/hip_bf16.h>

typedef __attribute__((ext_vector_type(8))) short short8;
typedef __attribute__((ext_vector_type(4))) short bf16x4;
typedef __attribute__((ext_vector_type(4))) float floatx4;

static __device__ __forceinline__ unsigned short f2bf(float f){
  // round-to-nearest-even fp32 -> bf16 (values are finite; no NaN path needed)
  unsigned int u = __float_as_uint(f);
  u += 0x7fffu + ((u >> 16) & 1u);
  return (unsigned short)(u >> 16);
}
static __device__ __forceinline__ float bf2f(unsigned short s){
  return __uint_as_float(((unsigned int)s) << 16);
}

// ---------------------------------------------------------------------------
// K1: W_eff = W_in @ W_tan  (stored TRANSPOSED as bf16 [64][800], K zero-padded
//     784->800), plus b_eff = b_in @ W_tan + b_tan (fp32 [64]).
// ---------------------------------------------------------------------------
__global__ void k1_weff(const float* __restrict__ W_in, const float* __restrict__ b_in,
                        const float* __restrict__ W_tan, const float* __restrict__ b_tan,
                        unsigned short* __restrict__ Wt, float* __restrict__ beff)
{
  int gid = blockIdx.x * 256 + threadIdx.x;   // 64*800 = 51200 threads
  if (gid < 64 * 800) {
    int n  = gid / 800;
    int kk = gid % 800;
    float acc = 0.f;
    if (kk < 784) {
      for (int m = 0; m < 128; ++m)
        acc += W_in[kk * 128 + m] * W_tan[m * 64 + n];
    }
    Wt[n * 800 + kk] = f2bf(acc);
  }
  if (gid < 64) {
    float b = b_tan[gid];
    for (int m = 0; m < 128; ++m)
      b += b_in[m] * W_tan[m * 64 + gid];
    beff[gid] = b;
  }
}

// ---------------------------------------------------------------------------
// K2: R = expm(A - A^T) via scaling-squaring Taylor (scale 1/256, 13 terms,
//     8 squarings), then fold W1eff = R0^T @ t0_w1, W2eff = R1^T @ t1_w1.
//     Matrices padded to 64x64 (zero pad => block-diag, exp of pad = I).
//     block 0 -> R0/W1eff, block 1 -> R1/W2eff.
// ---------------------------------------------------------------------------
__global__ __launch_bounds__(1024) void k2_expm(
    const float* __restrict__ A0, const float* __restrict__ A1,
    const float* __restrict__ t0w1, const float* __restrict__ t1w1,
    float* __restrict__ W1eff, float* __restrict__ W2eff)
{
  __shared__ float S[4096], P[4096], T[4096];
  const int tid = threadIdx.x;
  const int n = (blockIdx.x == 0) ? 64 : 48;
  const float* A = (blockIdx.x == 0) ? A0 : A1;
  const float sc = 1.0f / 256.0f;

  for (int e = tid; e < 4096; e += 1024) {
    int i = e >> 6, j = e & 63;
    float s = (i < n && j < n) ? (A[i * n + j] - A[j * n + i]) * sc : 0.f;
    S[e] = s; P[e] = s;
    T[e] = s + ((i == j) ? 1.f : 0.f);
  }
  __syncthreads();

  // Taylor terms 2..14
  for (int t = 2; t <= 14; ++t) {
    float inv = 1.0f / (float)t;
    float q[4];
    #pragma unroll
    for (int u = 0; u < 4; ++u) {
      int e = tid + u * 1024; int i = e >> 6, j = e & 63;
      float acc = 0.f;
      for (int k = 0; k < 64; ++k) acc += P[(i << 6) + k] * S[(k << 6) + j];
      q[u] = acc * inv;
    }
    __syncthreads();
    #pragma unroll
    for (int u = 0; u < 4; ++u) {
      int e = tid + u * 1024;
      P[e] = q[u]; T[e] += q[u];
    }
    __syncthreads();
  }
  // 8 squarings
  for (int sq = 0; sq < 8; ++sq) {
    float q[4];
    #pragma unroll
    for (int u = 0; u < 4; ++u) {
      int e = tid + u * 1024; int i = e >> 6, j = e & 63;
      float acc = 0.f;
      for (int k = 0; k < 64; ++k) acc += T[(i << 6) + k] * T[(k << 6) + j];
      q[u] = acc;
    }
    __syncthreads();
    #pragma unroll
    for (int u = 0; u < 4; ++u) T[tid + u * 1024] = q[u];
    __syncthreads();
  }

  // fold: Weff[a][j] = sum_b R[b][a] * w1[b][j]
  if (blockIdx.x == 0) {
    for (int idx = tid; idx < 64 * 56; idx += 1024) {
      int a_ = idx / 56, j = idx % 56;
      float acc = 0.f;
      for (int b = 0; b < 64; ++b) acc += T[(b << 6) + a_] * t0w1[b * 56 + j];
      W1eff[idx] = acc;
    }
  } else {
    for (int idx = tid; idx < 48 * 40; idx += 1024) {
      int a_ = idx / 40, j = idx % 40;
      float acc = 0.f;
      for (int b = 0; b < 48; ++b) acc += T[(b << 6) + a_] * t1w1[b * 40 + j];
      W2eff[idx] = acc;
    }
  }
}

// ---------------------------------------------------------------------------
// K3: v = x @ W_eff + b_eff  via bf16 MFMA 16x16x32, M=Bn, N=64, K=784(pad 800)
//     Direct-from-global fragments (no LDS): A layout A[m=lane&15][k=quad*8+j],
//     B layout B[n=lane&15][k=quad*8+j] from transposed Wt[64][800].
//     Output written TRANSPOSED bf16: vt[col][row], col-major for K4 coalescing.
//     Block = 256 thr = 4 waves; wave covers 64 rows (4 m-tiles x 4 n-tiles).
//     Epilogue packs 4 consecutive bf16 rows into one 8-B store (bf16x4).
// ---------------------------------------------------------------------------
__global__ __launch_bounds__(256) void k3_gemm(
    const float* __restrict__ x, const unsigned short* __restrict__ Wt,
    const float* __restrict__ beff, unsigned short* __restrict__ vt, int Bn)
{
  const int lane = threadIdx.x & 63;
  const int wave = threadIdx.x >> 6;
  const int m    = lane & 15;
  const int quad = lane >> 4;
  const size_t rowbase = (size_t)blockIdx.x * 256 + (size_t)wave * 64;

  floatx4 acc[4][4];
  #pragma unroll
  for (int a = 0; a < 4; ++a)
    #pragma unroll
    for (int b = 0; b < 4; ++b) acc[a][b] = (floatx4){0.f, 0.f, 0.f, 0.f};

  const float* xrow[4];
  #pragma unroll
  for (int mt = 0; mt < 4; ++mt)
    xrow[mt] = x + (rowbase + (size_t)(mt * 16 + m)) * 784;
  const unsigned short* wrow[4];
  #pragma unroll
  for (int nt = 0; nt < 4; ++nt)
    wrow[nt] = Wt + (size_t)(nt * 16 + m) * 800;

  for (int kc = 0; kc < 25; ++kc) {
    const int k0 = kc * 32 + quad * 8;
    const bool valid = (kc < 24) || (quad < 2);   // K remainder: 768..783 only
    short8 afrag[4];
    #pragma unroll
    for (int mt = 0; mt < 4; ++mt) {
      if (valid) {
        const float* xp = xrow[mt] + k0;
        floatx4 x0 = *(const floatx4*)(xp);
        floatx4 x1 = *(const floatx4*)(xp + 4);
        short8 t;
        t[0] = (short)f2bf(x0.x); t[1] = (short)f2bf(x0.y);
        t[2] = (short)f2bf(x0.z); t[3] = (short)f2bf(x0.w);
        t[4] = (short)f2bf(x1.x); t[5] = (short)f2bf(x1.y);
        t[6] = (short)f2bf(x1.z); t[7] = (short)f2bf(x1.w);
        afrag[mt] = t;
      } else {
        afrag[mt] = (short8){0,0,0,0,0,0,0,0};
      }
    }
    short8 bfrag[4];
    #pragma unroll
    for (int nt = 0; nt < 4; ++nt)
      bfrag[nt] = *(const short8*)(wrow[nt] + k0);   // zero-padded rows cover remainder
    #pragma unroll
    for (int mt = 0; mt < 4; ++mt)
      #pragma unroll
      for (int nt = 0; nt < 4; ++nt)
        acc[mt][nt] = __builtin_amdgcn_mfma_f32_16x16x32_bf16(
            afrag[mt], bfrag[nt], acc[mt][nt], 0, 0, 0);
  }

  // epilogue: C layout col=lane&15, row=quad*4+reg; 4 rg values are contiguous
  // ushorts in vt -> pack into one 8-B bf16x4 store (was 4x 2-B scalar stores).
  #pragma unroll
  for (int nt = 0; nt < 4; ++nt) {
    const int col = nt * 16 + m;
    const float bv = beff[col];
    unsigned short* vp = vt + (size_t)col * Bn + rowbase;
    #pragma unroll
    for (int mt = 0; mt < 4; ++mt) {
      bf16x4 pk;
      #pragma unroll
      for (int rg = 0; rg < 4; ++rg)
        pk[rg] = (short)f2bf(acc[mt][nt][rg] + bv);
      *(bf16x4*)(vp + mt * 16 + quad * 4) = pk;   // 8-B aligned
    }
  }
}

// ---------------------------------------------------------------------------
// K4: per-row chain, one thread per row, everything in registers (full unroll),
//     weights via wave-uniform scalar loads. _level == per-row scalar multiply.
// ---------------------------------------------------------------------------
static __device__ __forceinline__ float lvl_factor(float nv, float c, float s_in, float smin)
{
  const float EPS = 1e-7f;
  float s  = fmaxf(s_in, smin);
  float sq = sqrtf(c);
  float un = fmaxf(s * nv, EPS);        // |u|, u = v*s
  float a1 = sq * un;
  float t  = tanhf(a1);
  float f1 = t / a1;                    // expmap0 factor
  float en = s * nv * f1;               // |e|
  float maxn = (1.0f - 1e-5f) / sq;
  float xn = fmaxf(en, EPS);
  float p  = fminf(1.0f, maxn / xn);    // projx factor
  float xn2 = fmaxf(en * p, EPS);
  float arg = fminf(sq * xn2, 1.0f - 1e-7f);
  float ath = atanhf(arg);
  float f3 = ath / arg;                 // == ath/(sq*xn2), logmap0 factor
  return s * f1 * p * f3 / (s + EPS);
}

__global__ __launch_bounds__(256, 2) void k4_chain(
    const unsigned short* __restrict__ vt, int Bn,
    const float* __restrict__ W1eff, const float* __restrict__ w2a,
    const float* __restrict__ b1a,   const float* __restrict__ b2a,
    const float* __restrict__ W2eff, const float* __restrict__ w2b,
    const float* __restrict__ b1b,   const float* __restrict__ b2b,
    const float* __restrict__ Wout,  const float* __restrict__ bout,
    const float* __restrict__ s0p, const float* __restrict__ s1p,
    const float* __restrict__ s2p, float* __restrict__ out)
{
  const size_t r = (size_t)blockIdx.x * 256 + threadIdx.x;

  float v[64]; float ss = 0.f;
  #pragma unroll
  for (int k = 0; k < 64; ++k) {
    float f = bf2f(vt[(size_t)k * Bn + r]);
    v[k] = f; ss += f * f;
  }
  // level 0: c=1.0, smin=1e-4
  float f0 = lvl_factor(sqrtf(ss), 1.0f, s0p[0], 1e-4f);
  #pragma unroll
  for (int k = 0; k < 64; ++k) v[k] *= f0;   // v := t0

  float o[10];
  #pragma unroll
  for (int j = 0; j < 10; ++j) o[j] = bout[j];
  #pragma unroll
  for (int k = 0; k < 64; ++k) { float a = v[k];
    #pragma unroll
    for (int j = 0; j < 10; ++j) o[j] = fmaf(a, Wout[k * 10 + j], o[j]);
  }

  float h[56];
  #pragma unroll
  for (int j = 0; j < 56; ++j) h[j] = b1a[j];
  #pragma unroll
  for (int k = 0; k < 64; ++k) { float a = v[k];
    #pragma unroll
    for (int j = 0; j < 56; ++j) h[j] = fmaf(a, W1eff[k * 56 + j], h[j]);
  }

  float v1[48];
  #pragma unroll
  for (int j = 0; j < 48; ++j) v1[j] = b2a[j];
  #pragma unroll
  for (int k = 0; k < 56; ++k) { float a = fmaxf(h[k], 0.f);
    #pragma unroll
    for (int j = 0; j < 48; ++j) v1[j] = fmaf(a, w2a[k * 48 + j], v1[j]);
  }

  ss = 0.f;
  #pragma unroll
  for (int j = 0; j < 48; ++j) ss += v1[j] * v1[j];
  // level 1: c=0.8, smin=1e-5
  float f1 = lvl_factor(sqrtf(ss), 0.8f, s1p[0], 1e-5f);
  #pragma unroll
  for (int j = 0; j < 48; ++j) v1[j] *= f1;  // v1 := t1
  #pragma unroll
  for (int k = 0; k < 48; ++k) { float a = v1[k];
    #pragma unroll
    for (int j = 0; j < 10; ++j) o[j] = fmaf(a, Wout[(64 + k) * 10 + j], o[j]);
  }

  float h2[40];
  #pragma unroll
  for (int j = 0; j < 40; ++j) h2[j] = b1b[j];
  #pragma unroll
  for (int k = 0; k < 48; ++k) { float a = v1[k];
    #pragma unroll
    for (int j = 0; j < 40; ++j) h2[j] = fmaf(a, W2eff[k * 40 + j], h2[j]);
  }

  float v2[32];
  #pragma unroll
  for (int j = 0; j < 32; ++j) v2[j] = b2b[j];
  #pragma unroll
  for (int k = 0; k < 40; ++k) { float a = fmaxf(h2[k], 0.f);
    #pragma unroll
    for (int j = 0; j < 32; ++j) v2[j] = fmaf(a, w2b[k * 32 + j], v2[j]);
  }

  ss = 0.f;
  #pragma unroll
  for (int j = 0; j < 32; ++j) ss += v2[j] * v2[j];
  // level 2: c=1.2, smin=1e-6
  float f2 = lvl_factor(sqrtf(ss), 1.2f, s2p[0], 1e-6f);
  #pragma unroll
  for (int j = 0; j < 32; ++j) v2[j] *= f2;  // v2 := t2
  #pragma unroll
  for (int k = 0; k < 32; ++k) { float a = v2[k];
    #pragma unroll
    for (int j = 0; j < 10; ++j) o[j] = fmaf(a, Wout[(112 + k) * 10 + j], o[j]);
  }

  #pragma unroll
  for (int j = 0; j < 10; ++j) out[r * 10 + j] = o[j];
}

// ---------------------------------------------------------------------------
extern "C" void kernel_launch(void* const* d_in, const int* in_sizes, int n_in,
                              void* d_out, int out_size, void* d_ws, size_t ws_size,
                              hipStream_t stream)
{
  const float* x     = (const float*)d_in[0];
  const float* W_in  = (const float*)d_in[1];
  const float* b_in  = (const float*)d_in[2];
  const float* W_tan = (const float*)d_in[3];
  const float* b_tan = (const float*)d_in[4];
  const float* s0p   = (const float*)d_in[5];
  const float* s1p   = (const float*)d_in[6];
  const float* s2p   = (const float*)d_in[7];
  // d_in[8]=tp0, d_in[9]=tp1: boundary side-path, discarded by reference
  const float* A0    = (const float*)d_in[10];
  const float* A1    = (const float*)d_in[11];
  const float* t0w1  = (const float*)d_in[12];
  const float* t0b1  = (const float*)d_in[13];
  const float* t0w2  = (const float*)d_in[14];
  const float* t0b2  = (const float*)d_in[15];
  const float* t1w1  = (const float*)d_in[16];
  const float* t1b1  = (const float*)d_in[17];
  const float* t1w2  = (const float*)d_in[18];
  const float* t1b2  = (const float*)d_in[19];
  const float* Wout  = (const float*)d_in[20];
  const float* bout  = (const float*)d_in[21];
  float* out = (float*)d_out;
  const int Bn = in_sizes[0] / 784;

  char* ws = (char*)d_ws;
  unsigned short* Wt    = (unsigned short*)(ws);           // 64*800*2  = 102400 B
  float*          beff  = (float*)(ws + 102400);           // 256 B
  float*          W1eff = (float*)(ws + 102656);           // 64*56*4   = 14336 B
  float*          W2eff = (float*)(ws + 116992);           // 48*40*4   = 7680 B
  unsigned short* vt    = (unsigned short*)(ws + 131072);  // 64*Bn*2

  k1_weff<<<dim3(200), dim3(256), 0, stream>>>(W_in, b_in, W_tan, b_tan, Wt, beff);
  k2_expm<<<dim3(2), dim3(1024), 0, stream>>>(A0, A1, t0w1, t1w1, W1eff, W2eff);
  k3_gemm<<<dim3(Bn / 256), dim3(256), 0, stream>>>(x, Wt, beff, vt, Bn);
  k4_chain<<<dim3(Bn / 256), dim3(256), 0, stream>>>(vt, Bn, W1eff, t0w2, t0b1, t0b2,
                                                     W2eff, t1w2, t1b1, t1b2,
                                                     Wout, bout, s0p, s1p, s2p, out);
}